// Round 1
// baseline (22974.759 us; speedup 1.0000x reference)
//
#include <hip/hip_runtime.h>

#define BB 32768
#define DD 128
#define HH 512

__global__ __launch_bounds__(256) void cnf_fused_kernel(
    const float* __restrict__ x, const float* __restrict__ logpx,
    const float* __restrict__ cond, const float* __restrict__ e,
    const float* __restrict__ W1, const float* __restrict__ Wc,
    const float* __restrict__ bt, const float* __restrict__ b1,
    const float* __restrict__ W2, const float* __restrict__ b2,
    float* __restrict__ y_out, float* __restrict__ lp_out)
{
    const int wave = threadIdx.x >> 6;
    const int lane = threadIdx.x & 63;
    const int row  = (blockIdx.x << 2) + wave;

    __shared__ float s_xx[4][DD];
    __shared__ float s_h[4][HH];
    __shared__ float s_g[4][HH];

    const float dt = 0.25f;   // INTERVAL / N_STEPS

    // per-lane persistent state (lane owns elements lane and lane+64 of D=128,
    // and elements lane+64*j, j=0..7 of H=512)
    const float e0 = e[row*DD + lane];
    const float e1 = e[row*DD + 64 + lane];
    float xs0 = x[row*DD + lane];
    float xs1 = x[row*DD + 64 + lane];
    const float b2r0 = b2[lane];
    const float b2r1 = b2[lane + 64];

    float btr[8], baser[8], vr[8];
    #pragma unroll
    for (int j = 0; j < 8; ++j) btr[j] = bt[lane + 64*j];

    // ---- base = cond@Wc + b1  (scratch: cond row in s_xx) ----
    s_xx[wave][lane]      = cond[row*DD + lane];        // C == 128 == D
    s_xx[wave][lane + 64] = cond[row*DD + 64 + lane];
    __syncthreads();
    #pragma unroll
    for (int j = 0; j < 8; ++j) baser[j] = b1[lane + 64*j];
    for (int i = 0; i < DD; ++i) {
        const float cv = s_xx[wave][i];
        #pragma unroll
        for (int j = 0; j < 8; ++j)
            baser[j] += cv * Wc[i*HH + lane + 64*j];
    }
    __syncthreads();

    // ---- v = e @ W2^T  (scratch: e row in s_xx) ----
    s_xx[wave][lane]      = e0;
    s_xx[wave][lane + 64] = e1;
    __syncthreads();
    #pragma unroll
    for (int j = 0; j < 8; ++j) vr[j] = 0.f;
    for (int i = 0; i < DD; ++i) {
        const float ev = s_xx[wave][i];
        #pragma unroll
        for (int j = 0; j < 8; ++j)
            vr[j] += ev * W2[(lane + 64*j)*DD + i];
    }
    __syncthreads();

    // ---- xx = x ----
    s_xx[wave][lane]      = xs0;
    s_xx[wave][lane + 64] = xs1;
    __syncthreads();

    float divacc = 0.f;   // sum over all 16 stages of w * div, w in {1,2,2,1}

    for (int step = 0; step < 4; ++step) {
        const float t0 = dt * (float)step;
        float dxc0 = 0.f, dxc1 = 0.f;
        #pragma unroll 1
        for (int st = 0; st < 4; ++st) {
            const float t = t0 + ((st == 0) ? 0.f : (st == 3) ? dt : 0.5f*dt);
            const float w = (st == 1 || st == 2) ? 2.f : 1.f;

            // GEMM1: pre = xx@W1 + base + t*bt ; h = tanh(pre) ; g = (1-h^2)*v
            float pre[8];
            #pragma unroll
            for (int j = 0; j < 8; ++j) pre[j] = baser[j] + t*btr[j];
            #pragma unroll 4
            for (int i = 0; i < DD; ++i) {
                const float xv = s_xx[wave][i];
                #pragma unroll
                for (int j = 0; j < 8; ++j)
                    pre[j] += xv * W1[i*HH + lane + 64*j];
            }
            #pragma unroll
            for (int j = 0; j < 8; ++j) {
                const float h = tanhf(pre[j]);
                s_h[wave][lane + 64*j] = h;
                s_g[wave][lane + 64*j] = (1.f - h*h) * vr[j];
            }
            __syncthreads();

            // GEMM2: dx = h@W2 + b2 ; GEMM3: u = g@W1^T ; div = sum(u*e)
            float dx0 = b2r0, dx1 = b2r1, u0 = 0.f, u1 = 0.f;
            const float4* hp  = (const float4*)(&s_h[wave][0]);
            const float4* gp  = (const float4*)(&s_g[wave][0]);
            const float4* w1a = (const float4*)(W1 + (size_t)lane*HH);
            const float4* w1b = (const float4*)(W1 + (size_t)(lane+64)*HH);
            #pragma unroll 2
            for (int kk = 0; kk < HH/4; ++kk) {
                const float4 hv = hp[kk], gv = gp[kk];
                const float4 wa = w1a[kk], wb = w1b[kk];
                const int k = kk*4;
                dx0 += hv.x * W2[(k+0)*DD + lane];
                dx1 += hv.x * W2[(k+0)*DD + 64 + lane];
                dx0 += hv.y * W2[(k+1)*DD + lane];
                dx1 += hv.y * W2[(k+1)*DD + 64 + lane];
                dx0 += hv.z * W2[(k+2)*DD + lane];
                dx1 += hv.z * W2[(k+2)*DD + 64 + lane];
                dx0 += hv.w * W2[(k+3)*DD + lane];
                dx1 += hv.w * W2[(k+3)*DD + 64 + lane];
                u0 += gv.x*wa.x + gv.y*wa.y + gv.z*wa.z + gv.w*wa.w;
                u1 += gv.x*wb.x + gv.y*wb.y + gv.z*wb.z + gv.w*wb.w;
            }
            divacc += w * (u0*e0 + u1*e1);
            dxc0 += w*dx0;  dxc1 += w*dx1;
            __syncthreads();
            if (st < 3) {
                const float a = (st == 2) ? 1.f : 0.5f;
                s_xx[wave][lane]      = xs0 + a*dt*dx0;
                s_xx[wave][lane + 64] = xs1 + a*dt*dx1;
            } else {
                xs0 += dt*dxc0*(1.f/6.f);
                xs1 += dt*dxc1*(1.f/6.f);
                s_xx[wave][lane]      = xs0;   // next step's xx
                s_xx[wave][lane + 64] = xs1;
            }
            __syncthreads();
        }
    }

    // outputs: y then logpy (reg term is exactly zero in forward)
    y_out[row*DD + lane]      = xs0;
    y_out[row*DD + 64 + lane] = xs1;
    #pragma unroll
    for (int off = 32; off > 0; off >>= 1)
        divacc += __shfl_xor(divacc, off);
    if (lane == 0)
        lp_out[row] = logpx[row] - dt*divacc*(1.f/6.f);
}

extern "C" void kernel_launch(void* const* d_in, const int* in_sizes, int n_in,
                              void* d_out, int out_size, void* d_ws, size_t ws_size,
                              hipStream_t stream) {
    const float* x     = (const float*)d_in[0];
    const float* logpx = (const float*)d_in[1];
    const float* cond  = (const float*)d_in[2];
    const float* e     = (const float*)d_in[3];
    const float* W1    = (const float*)d_in[4];
    const float* Wc    = (const float*)d_in[5];
    const float* bt    = (const float*)d_in[6];
    const float* b1    = (const float*)d_in[7];
    const float* W2    = (const float*)d_in[8];
    const float* b2    = (const float*)d_in[9];

    float* y_out  = (float*)d_out;
    float* lp_out = y_out + (size_t)BB*DD;

    dim3 grid(BB/4), block(256);
    hipLaunchKernelGGL(cnf_fused_kernel, grid, block, 0, stream,
                       x, logpx, cond, e, W1, Wc, bt, b1, W2, b2, y_out, lp_out);
}

// Round 2
// 2100.869 us; speedup vs baseline: 10.9358x; 10.9358x over previous
//
#include <hip/hip_runtime.h>

typedef unsigned short u16;
typedef __attribute__((ext_vector_type(8))) short bf16x8;
typedef __attribute__((ext_vector_type(4))) float f32x4;

#define MFMA16(A,B,C) __builtin_amdgcn_mfma_f32_16x16x32_bf16(A,B,C,0,0,0)

__device__ __forceinline__ u16 f2bf(float f){
    unsigned int u = __float_as_uint(f);
    u += 0x7fffu + ((u >> 16) & 1u);
    return (u16)(u >> 16);
}
__device__ __forceinline__ unsigned int pk2(float lo, float hi){
    return (unsigned int)f2bf(lo) | ((unsigned int)f2bf(hi) << 16);
}
__device__ __forceinline__ float upk(unsigned int u, int hi){
    return __uint_as_float(hi ? (u & 0xffff0000u) : (u << 16));
}
__device__ __forceinline__ float fast_tanh(float p){
    float e2 = __expf(2.f * p);
    return 1.f - __fdividef(2.f, e2 + 1.f);
}
__device__ __forceinline__ void gload16(const u16* g, u16* l){
    __builtin_amdgcn_global_load_lds((const __attribute__((address_space(1))) void*)g,
                                     (__attribute__((address_space(3))) void*)l, 16, 0, 0);
}

// ---------------- weight pre-pack kernel ----------------
// ws layout (u16 each 65536): [0]=W1 (GEMM1 B), [1]=W2 (GEMM2 B), [2]=W1T (GEMM3 B),
//                             [3]=W2T (vGEMM B), [4]=Wc (baseGEMM B)
// Style A (K=128,N=512; packs 0,3,4): q = nc(3b)|ks(2b)|t(2b)|l(6b)|j(3b)
// Style B (K=512,N=128; packs 1,2):   q = nc(3b)|ksl(1b)|nt(3b)|l(6b)|j(3b)
__global__ __launch_bounds__(256) void pack_weights_kernel(
    const float* __restrict__ W1, const float* __restrict__ W2,
    const float* __restrict__ Wc, u16* __restrict__ wp)
{
    int p = blockIdx.x * 256 + threadIdx.x;        // 0 .. 5*65536-1
    int which = p >> 16;
    int q = p & 65535;
    int j = q & 7, l = (q >> 3) & 63;
    int l15 = l & 15, l4 = l >> 4;
    float v;
    if (which == 0 || which == 3 || which == 4) {
        int t = (q >> 9) & 3, ks = (q >> 11) & 3, nc = q >> 13;
        int k = 32 * ks + l4 * 8 + j;
        int n = 64 * nc + 16 * t + l15;
        v = (which == 0) ? W1[k * 512 + n] : (which == 3) ? W2[n * 128 + k] : Wc[k * 512 + n];
    } else {
        int nt = (q >> 9) & 7, ksl = (q >> 12) & 1, nc = q >> 13;
        int k = 64 * nc + 32 * ksl + l4 * 8 + j;
        int n = 16 * nt + l15;
        v = (which == 1) ? W2[k * 128 + n] : W1[n * 512 + k];
    }
    wp[p] = f2bf(v);
}

// ---------------- fused CNF RK4 kernel ----------------
__global__ __launch_bounds__(256, 1) void cnf_mfma_kernel(
    const float* __restrict__ x, const float* __restrict__ logpx,
    const float* __restrict__ cond, const float* __restrict__ e,
    const float* __restrict__ bt, const float* __restrict__ b1,
    const float* __restrict__ b2, const u16* __restrict__ wp,
    float* __restrict__ y_out, float* __restrict__ lp_out)
{
    __shared__ u16 s_w[2][3 * 8192];     // 96 KB: staged weight chunks
    __shared__ u16 s_xx[4][16 * 136];    // per-wave xx tile (pad 128->136)
    __shared__ u16 s_h[4][16 * 72];      // per-wave h chunk (pad 64->72)
    __shared__ u16 s_g[4][16 * 72];

    const int tid = threadIdx.x;
    const int wave = tid >> 6, lane = tid & 63;
    const int l15 = lane & 15, l4 = lane >> 4;
    const int rbase = blockIdx.x * 64 + wave * 16;

    const u16* W1p  = wp;
    const u16* W2p  = wp + 65536;
    const u16* W1Tp = wp + 131072;
    const u16* W2Tp = wp + 196608;
    const u16* Wcp  = wp + 262144;

    u16* xxw = &s_xx[wave][0];
    u16* hw  = &s_h[wave][0];
    u16* gw  = &s_g[wave][0];

    // stage 16KB chunk of W2T+Wc packs into s_w[buf] (prologue GEMMs)
    auto stage2 = [&](int buf, int nc){
        #pragma unroll
        for (int q = 0; q < 4; ++q){
            const int blk = wave * 4 + q;
            const int goff = nc * 8192 + blk * 512 + lane * 8;
            gload16(W2Tp + goff, &s_w[buf][blk * 512]);
            gload16(Wcp  + goff, &s_w[buf][8192 + blk * 512]);
        }
    };
    // stage 48KB chunk of W1+W2+W1T packs into s_w[buf] (main loop)
    auto stage3 = [&](int buf, int nc){
        #pragma unroll
        for (int q = 0; q < 4; ++q){
            const int blk = wave * 4 + q;
            const int goff = nc * 8192 + blk * 512 + lane * 8;
            gload16(W1p  + goff, &s_w[buf][blk * 512]);
            gload16(W2p  + goff, &s_w[buf][8192  + blk * 512]);
            gload16(W1Tp + goff, &s_w[buf][16384 + blk * 512]);
        }
    };

    stage2(0, 0);   // first prefetch ASAP

    // ---- per-lane C-layout constants ----
    float xs[8][4], e_c[8][4], b2v[8];
    #pragma unroll
    for (int nt = 0; nt < 8; ++nt){
        #pragma unroll
        for (int r = 0; r < 4; ++r){
            const int row = rbase + l4 * 4 + r, col = nt * 16 + l15;
            xs[nt][r]  = x[row * 128 + col];
            e_c[nt][r] = e[row * 128 + col];
        }
        b2v[nt] = b2[nt * 16 + l15];
    }

    // ---- stage e -> xxw, read e A-frags; same for cond; then x -> xxw ----
    #pragma unroll
    for (int i = 0; i < 32; ++i){
        int flat = i * 64 + lane;
        int row = flat >> 7, col = flat & 127;
        xxw[row * 136 + col] = f2bf(e[(rbase + row) * 128 + col]);
    }
    bf16x8 eA[4];
    #pragma unroll
    for (int ks = 0; ks < 4; ++ks)
        eA[ks] = *(const bf16x8*)&xxw[l15 * 136 + ks * 32 + l4 * 8];
    #pragma unroll
    for (int i = 0; i < 32; ++i){
        int flat = i * 64 + lane;
        int row = flat >> 7, col = flat & 127;
        xxw[row * 136 + col] = f2bf(cond[(rbase + row) * 128 + col]);
    }
    bf16x8 cA[4];
    #pragma unroll
    for (int ks = 0; ks < 4; ++ks)
        cA[ks] = *(const bf16x8*)&xxw[l15 * 136 + ks * 32 + l4 * 8];
    #pragma unroll
    for (int nt = 0; nt < 8; ++nt)
        #pragma unroll
        for (int r = 0; r < 4; ++r)
            xxw[(l4 * 4 + r) * 136 + nt * 16 + l15] = f2bf(xs[nt][r]);

    // ---- prologue GEMMs: v = e@W2T, base = cond@Wc + b1 (packed bf16 in regs) ----
    unsigned int v_pk[8][4][2], base_pk[8][4][2];
    #pragma unroll
    for (int nc = 0; nc < 8; ++nc){
        const int buf = nc & 1;
        asm volatile("s_waitcnt vmcnt(0)" ::: "memory");
        __syncthreads();
        if (nc < 7) stage2(buf ^ 1, nc + 1);
        else        stage3(buf ^ 1, 0);           // prefetch main chunk 0
        f32x4 av[4], ab[4];
        #pragma unroll
        for (int t = 0; t < 4; ++t){ av[t] = {0.f,0.f,0.f,0.f}; ab[t] = {0.f,0.f,0.f,0.f}; }
        #pragma unroll
        for (int ks = 0; ks < 4; ++ks){
            #pragma unroll
            for (int t = 0; t < 4; ++t){
                bf16x8 bv = *(const bf16x8*)&s_w[buf][(ks * 4 + t) * 512 + lane * 8];
                av[t] = MFMA16(eA[ks], bv, av[t]);
                bf16x8 bb = *(const bf16x8*)&s_w[buf][8192 + (ks * 4 + t) * 512 + lane * 8];
                ab[t] = MFMA16(cA[ks], bb, ab[t]);
            }
        }
        #pragma unroll
        for (int t = 0; t < 4; ++t){
            float b1v = b1[nc * 64 + t * 16 + l15];
            #pragma unroll
            for (int rr = 0; rr < 2; ++rr){
                v_pk[nc][t][rr]    = pk2(av[t][2 * rr], av[t][2 * rr + 1]);
                base_pk[nc][t][rr] = pk2(ab[t][2 * rr] + b1v, ab[t][2 * rr + 1] + b1v);
            }
        }
    }

    // ---- main RK4 loop: 16 stages x 8 chunks ----
    f32x4 acc_dx[8], acc_u[8];
    float dxc[8][4], divacc[4];
    #pragma unroll
    for (int nt = 0; nt < 8; ++nt){
        acc_dx[nt] = {0.f,0.f,0.f,0.f};
        acc_u[nt]  = {0.f,0.f,0.f,0.f};
        #pragma unroll
        for (int r = 0; r < 4; ++r) dxc[nt][r] = 0.f;
    }
    #pragma unroll
    for (int r = 0; r < 4; ++r) divacc[r] = 0.f;

    #pragma unroll 1
    for (int st = 0; st < 16; ++st){
        const int stg = st & 3;
        const float tcur = 0.25f * (float)(st >> 2) + ((stg == 0) ? 0.f : ((stg == 3) ? 0.25f : 0.125f));
        const float wcur = (stg == 1 || stg == 2) ? 2.f : 1.f;

        bf16x8 xxA[4];
        #pragma unroll
        for (int ks = 0; ks < 4; ++ks)
            xxA[ks] = *(const bf16x8*)&xxw[l15 * 136 + ks * 32 + l4 * 8];

        #pragma unroll
        for (int nc = 0; nc < 8; ++nc){
            const int buf = nc & 1;
            asm volatile("s_waitcnt vmcnt(0)" ::: "memory");
            __syncthreads();
            if (!(st == 15 && nc == 7)) stage3(buf ^ 1, (nc + 1) & 7);

            // GEMM1: pre = xx@W1 + base + t*bt
            f32x4 pre[4];
            #pragma unroll
            for (int t = 0; t < 4; ++t){
                float btv = bt[nc * 64 + t * 16 + l15];
                #pragma unroll
                for (int r = 0; r < 4; ++r)
                    pre[t][r] = upk(base_pk[nc][t][r >> 1], r & 1) + tcur * btv;
            }
            #pragma unroll
            for (int ks = 0; ks < 4; ++ks){
                #pragma unroll
                for (int t = 0; t < 4; ++t){
                    bf16x8 bw = *(const bf16x8*)&s_w[buf][(ks * 4 + t) * 512 + lane * 8];
                    pre[t] = MFMA16(xxA[ks], bw, pre[t]);
                }
            }
            // h = tanh(pre), g = (1-h^2)*v  -> wave-private LDS (C-layout scatter)
            #pragma unroll
            for (int t = 0; t < 4; ++t){
                #pragma unroll
                for (int r = 0; r < 4; ++r){
                    float h = fast_tanh(pre[t][r]);
                    float g = (1.f - h * h) * upk(v_pk[nc][t][r >> 1], r & 1);
                    const int row = l4 * 4 + r, col = t * 16 + l15;
                    hw[row * 72 + col] = f2bf(h);
                    gw[row * 72 + col] = f2bf(g);
                }
            }
            // GEMM2: dx += h@W2 ; GEMM3: u += g@W1T   (K-slice of 64)
            #pragma unroll
            for (int ksl = 0; ksl < 2; ++ksl){
                bf16x8 hA = *(const bf16x8*)&hw[l15 * 72 + ksl * 32 + l4 * 8];
                bf16x8 gA = *(const bf16x8*)&gw[l15 * 72 + ksl * 32 + l4 * 8];
                #pragma unroll
                for (int nt = 0; nt < 8; ++nt){
                    bf16x8 w2f  = *(const bf16x8*)&s_w[buf][8192  + (ksl * 8 + nt) * 512 + lane * 8];
                    acc_dx[nt] = MFMA16(hA, w2f, acc_dx[nt]);
                    bf16x8 w1tf = *(const bf16x8*)&s_w[buf][16384 + (ksl * 8 + nt) * 512 + lane * 8];
                    acc_u[nt]  = MFMA16(gA, w1tf, acc_u[nt]);
                }
            }
        }

        // ---- stage epilogue: div, RK4 combine, next xx ----
        const float adt = (stg == 2) ? 0.25f : 0.125f;   // a*dt for stg 0,1 (0.125) / 2 (0.25)
        #pragma unroll
        for (int nt = 0; nt < 8; ++nt){
            #pragma unroll
            for (int r = 0; r < 4; ++r){
                float dxf = acc_dx[nt][r] + b2v[nt];
                divacc[r] += wcur * acc_u[nt][r] * e_c[nt][r];
                dxc[nt][r] += wcur * dxf;
                float xnew;
                if (stg < 3) xnew = xs[nt][r] + adt * dxf;
                else { xs[nt][r] += (0.25f / 6.f) * dxc[nt][r]; dxc[nt][r] = 0.f; xnew = xs[nt][r]; }
                xxw[(l4 * 4 + r) * 136 + nt * 16 + l15] = f2bf(xnew);
                acc_dx[nt][r] = 0.f;
                acc_u[nt][r]  = 0.f;
            }
        }
    }

    // ---- outputs ----
    #pragma unroll
    for (int nt = 0; nt < 8; ++nt)
        #pragma unroll
        for (int r = 0; r < 4; ++r)
            y_out[(rbase + l4 * 4 + r) * 128 + nt * 16 + l15] = xs[nt][r];

    #pragma unroll
    for (int r = 0; r < 4; ++r){
        float d = divacc[r];
        d += __shfl_xor(d, 1);
        d += __shfl_xor(d, 2);
        d += __shfl_xor(d, 4);
        d += __shfl_xor(d, 8);
        if (l15 == 0){
            const int row = rbase + l4 * 4 + r;
            lp_out[row] = logpx[row] - (0.25f / 6.f) * d;
        }
    }
}

extern "C" void kernel_launch(void* const* d_in, const int* in_sizes, int n_in,
                              void* d_out, int out_size, void* d_ws, size_t ws_size,
                              hipStream_t stream) {
    const float* x     = (const float*)d_in[0];
    const float* logpx = (const float*)d_in[1];
    const float* cond  = (const float*)d_in[2];
    const float* e     = (const float*)d_in[3];
    const float* W1    = (const float*)d_in[4];
    const float* Wc    = (const float*)d_in[5];
    const float* bt    = (const float*)d_in[6];
    const float* b1    = (const float*)d_in[7];
    const float* W2    = (const float*)d_in[8];
    const float* b2    = (const float*)d_in[9];

    u16* wp = (u16*)d_ws;                       // 5*65536 u16 = 640 KB
    float* y_out  = (float*)d_out;
    float* lp_out = y_out + (size_t)32768 * 128;

    hipLaunchKernelGGL(pack_weights_kernel, dim3(1280), dim3(256), 0, stream, W1, W2, Wc, wp);
    hipLaunchKernelGGL(cnf_mfma_kernel, dim3(512), dim3(256), 0, stream,
                       x, logpx, cond, e, bt, b1, b2, wp, y_out, lp_out);
}

// Round 3
// 1590.772 us; speedup vs baseline: 14.4425x; 1.3207x over previous
//
#include <hip/hip_runtime.h>

typedef unsigned short u16;
typedef __attribute__((ext_vector_type(8))) short bf16x8;
typedef __attribute__((ext_vector_type(4))) float f32x4;

#define MFMA16(A,B,C) __builtin_amdgcn_mfma_f32_16x16x32_bf16(A,B,C,0,0,0)

__device__ __forceinline__ u16 f2bf(float f){
    unsigned int u = __float_as_uint(f);
    u += 0x7fffu + ((u >> 16) & 1u);
    return (u16)(u >> 16);
}
__device__ __forceinline__ unsigned int pk2(float lo, float hi){
    return (unsigned int)f2bf(lo) | ((unsigned int)f2bf(hi) << 16);
}
__device__ __forceinline__ float upk(unsigned int u, int hi){
    return __uint_as_float(hi ? (u & 0xffff0000u) : (u << 16));
}
__device__ __forceinline__ float bf2f(u16 v){
    return __uint_as_float(((unsigned int)v) << 16);
}
__device__ __forceinline__ float fast_tanh(float p){
    float e2 = __expf(2.f * p);
    return 1.f - __fdividef(2.f, e2 + 1.f);
}
__device__ __forceinline__ void gload16(const u16* g, u16* l){
    __builtin_amdgcn_global_load_lds((const __attribute__((address_space(1))) void*)g,
                                     (__attribute__((address_space(3))) void*)l, 16, 0, 0);
}

// ---------------- weight pre-pack kernel ----------------
// ws layout (u16 each 65536): [0]=W1 (B for xx@W1 / e@W1), [1]=W2 (B for h@W2),
//                             [2]=unused, [3]=W2T (B for e@W2T), [4]=Wc (B for cond@Wc)
// Style A (K=128,N=512; 0,3,4): q = nc(3b)|ks(2b)|t(2b)|l(6b)|j(3b)
// Style B (K=512,N=128; 1):     q = nc(3b)|ksl(1b)|nt(3b)|l(6b)|j(3b)
__global__ __launch_bounds__(256) void pack_weights_kernel(
    const float* __restrict__ W1, const float* __restrict__ W2,
    const float* __restrict__ Wc, u16* __restrict__ wp)
{
    int p = blockIdx.x * 256 + threadIdx.x;        // 0 .. 5*65536-1
    int which = p >> 16;
    int q = p & 65535;
    int j = q & 7, l = (q >> 3) & 63;
    int l15 = l & 15, l4 = l >> 4;
    float v;
    if (which == 0 || which == 3 || which == 4) {
        int t = (q >> 9) & 3, ks = (q >> 11) & 3, nc = q >> 13;
        int k = 32 * ks + l4 * 8 + j;
        int n = 64 * nc + 16 * t + l15;
        v = (which == 0) ? W1[k * 512 + n] : (which == 3) ? W2[n * 128 + k] : Wc[k * 512 + n];
    } else {
        int nt = (q >> 9) & 7, ksl = (q >> 12) & 1, nc = q >> 13;
        int k = 64 * nc + 32 * ksl + l4 * 8 + j;
        int n = 16 * nt + l15;
        v = (which == 1) ? W2[k * 128 + n] : W1[n * 512 + k];
    }
    wp[p] = f2bf(v);
}

// ---------------- fused CNF RK4 kernel ----------------
__global__ __launch_bounds__(256, 2) void cnf_mfma2_kernel(
    const float* __restrict__ x, const float* __restrict__ logpx,
    const float* __restrict__ cond, const float* __restrict__ e,
    const float* __restrict__ b1, const u16* __restrict__ wp,
    const float* __restrict__ bt, const float* __restrict__ b2,
    float* __restrict__ y_out, float* __restrict__ lp_out)
{
    __shared__ u16 s_w[2][2 * 8192];   // 64 KB double-buffered weight chunks
    __shared__ u16 s_t[4][16 * 72];    // 9 KB per-wave transpose buffers
    __shared__ u16 s_bt[512];
    __shared__ float s_b2[128];

    const int tid = threadIdx.x, wave = tid >> 6, lane = tid & 63;
    const int l15 = lane & 15, l4 = lane >> 4;
    const int rbase = blockIdx.x * 64 + wave * 16;

    const u16* W1p  = wp;
    const u16* W2p  = wp + 65536;
    const u16* W2Tp = wp + 196608;
    const u16* Wcp  = wp + 262144;
    u16* tw = &s_t[wave][0];

    auto stage_main = [&](int buf, int nc){   // W1[nc] -> slot0, W2[nc] -> slot1 (32 KB)
        #pragma unroll
        for (int q = 0; q < 8; ++q){
            const int idx = wave * 8 + q;     // 0..31
            const u16* src = (idx < 16) ? (W1p + nc * 8192 + idx * 512)
                                        : (W2p + nc * 8192 + (idx - 16) * 512);
            gload16(src + lane * 8, &s_w[buf][idx * 512]);
        }
    };
    auto stage_proA = [&](int buf, int nc){   // W1[nc] -> slot0, Wc[nc] -> slot1
        #pragma unroll
        for (int q = 0; q < 8; ++q){
            const int idx = wave * 8 + q;
            const u16* src = (idx < 16) ? (W1p + nc * 8192 + idx * 512)
                                        : (Wcp + nc * 8192 + (idx - 16) * 512);
            gload16(src + lane * 8, &s_w[buf][idx * 512]);
        }
    };
    auto stage_proB = [&](int buf, int nc){   // W2T[nc] -> slot0 (16 KB)
        #pragma unroll
        for (int q = 0; q < 4; ++q){
            const int idx = wave * 4 + q;     // 0..15
            gload16(W2Tp + nc * 8192 + idx * 512 + lane * 8, &s_w[buf][idx * 512]);
        }
    };

    // constant vectors to LDS + first prefetch
    s_bt[tid]       = f2bf(bt[tid]);
    s_bt[tid + 256] = f2bf(bt[tid + 256]);
    if (tid < 128) s_b2[tid] = b2[tid];
    stage_proA(0, 0);

    // ---- xs in C-layout ----
    float xs[8][4];
    #pragma unroll
    for (int nt = 0; nt < 8; ++nt)
        #pragma unroll
        for (int r = 0; r < 4; ++r)
            xs[nt][r] = x[(size_t)(rbase + l4 * 4 + r) * 128 + nt * 16 + l15];

    // ---- build eA, cA, xxA fragments via wave-private transpose buffer ----
    bf16x8 eA[4], cA[4], xxA[4];
    #pragma unroll
    for (int p = 0; p < 2; ++p){
        #pragma unroll
        for (int i = 0; i < 16; ++i)
            tw[i * 72 + lane] = f2bf(e[(size_t)(rbase + i) * 128 + p * 64 + lane]);
        #pragma unroll
        for (int ksl = 0; ksl < 2; ++ksl)
            eA[p * 2 + ksl] = *(const bf16x8*)&tw[l15 * 72 + ksl * 32 + l4 * 8];
        #pragma unroll
        for (int i = 0; i < 16; ++i)
            tw[i * 72 + lane] = f2bf(cond[(size_t)(rbase + i) * 128 + p * 64 + lane]);
        #pragma unroll
        for (int ksl = 0; ksl < 2; ++ksl)
            cA[p * 2 + ksl] = *(const bf16x8*)&tw[l15 * 72 + ksl * 32 + l4 * 8];
        #pragma unroll
        for (int t = 0; t < 4; ++t)
            #pragma unroll
            for (int r = 0; r < 4; ++r)
                tw[(l4 * 4 + r) * 72 + t * 16 + l15] = f2bf(xs[p * 4 + t][r]);
        #pragma unroll
        for (int ksl = 0; ksl < 2; ++ksl)
            xxA[p * 2 + ksl] = *(const bf16x8*)&tw[l15 * 72 + ksl * 32 + l4 * 8];
    }

    // ---- prologue: base = cond@Wc + b1, q = (e@W1) ⊙ (e@W2T), packed bf16 ----
    unsigned int base_pk[8][4][2], q_pk[8][4][2];
    #pragma unroll
    for (int nc = 0; nc < 8; ++nc){
        __syncthreads();
        stage_proB(1, nc);                       // prefetch W2T[nc] into buf1
        f32x4 ew1[4], ab[4];
        #pragma unroll
        for (int t = 0; t < 4; ++t){ ew1[t] = {0.f,0.f,0.f,0.f}; ab[t] = {0.f,0.f,0.f,0.f}; }
        #pragma unroll
        for (int ks = 0; ks < 4; ++ks)
            #pragma unroll
            for (int t = 0; t < 4; ++t){
                ew1[t] = MFMA16(eA[ks], *(const bf16x8*)&s_w[0][(ks * 4 + t) * 512 + lane * 8], ew1[t]);
                ab[t]  = MFMA16(cA[ks], *(const bf16x8*)&s_w[0][8192 + (ks * 4 + t) * 512 + lane * 8], ab[t]);
            }
        #pragma unroll
        for (int t = 0; t < 4; ++t){
            float b1v = b1[nc * 64 + t * 16 + l15];
            #pragma unroll
            for (int rr = 0; rr < 2; ++rr)
                base_pk[nc][t][rr] = pk2(ab[t][2 * rr] + b1v, ab[t][2 * rr + 1] + b1v);
        }
        __syncthreads();
        if (nc < 7) stage_proA(0, nc + 1);       // prefetch next W1/Wc into buf0
        else        stage_main(0, 0);            // prefetch main chunk 0
        f32x4 e2[4];
        #pragma unroll
        for (int t = 0; t < 4; ++t) e2[t] = {0.f,0.f,0.f,0.f};
        #pragma unroll
        for (int ks = 0; ks < 4; ++ks)
            #pragma unroll
            for (int t = 0; t < 4; ++t)
                e2[t] = MFMA16(eA[ks], *(const bf16x8*)&s_w[1][(ks * 4 + t) * 512 + lane * 8], e2[t]);
        #pragma unroll
        for (int t = 0; t < 4; ++t)
            #pragma unroll
            for (int rr = 0; rr < 2; ++rr)
                q_pk[nc][t][rr] = pk2(ew1[t][2 * rr] * e2[t][2 * rr],
                                      ew1[t][2 * rr + 1] * e2[t][2 * rr + 1]);
    }

    // ---- main RK4 loop ----
    f32x4 acc[8];
    unsigned int dxc_pk[8][2];
    float divacc[4] = {0.f, 0.f, 0.f, 0.f};
    #pragma unroll
    for (int nt = 0; nt < 8; ++nt){
        acc[nt] = {0.f,0.f,0.f,0.f};
        dxc_pk[nt][0] = 0u; dxc_pk[nt][1] = 0u;
    }

    #pragma unroll 1
    for (int st = 0; st < 16; ++st){
        const int stg = st & 3;
        const float tcur = 0.25f * (float)(st >> 2) + ((stg == 0) ? 0.f : (stg == 3) ? 0.25f : 0.125f);
        const float wcur = (stg == 1 || stg == 2) ? 2.f : 1.f;
        float divst[4] = {0.f, 0.f, 0.f, 0.f};

        #pragma unroll
        for (int nc = 0; nc < 8; ++nc){
            const int buf = nc & 1;
            __syncthreads();
            if (!(st == 15 && nc == 7)) stage_main(buf ^ 1, (nc + 1) & 7);

            // GEMM1: pre = xx@W1 + base + t*bt
            f32x4 pre[4];
            #pragma unroll
            for (int t = 0; t < 4; ++t){
                const float btv = bf2f(s_bt[nc * 64 + t * 16 + l15]);
                #pragma unroll
                for (int r = 0; r < 4; ++r)
                    pre[t][r] = upk(base_pk[nc][t][r >> 1], r & 1) + tcur * btv;
            }
            #pragma unroll
            for (int ks = 0; ks < 4; ++ks)
                #pragma unroll
                for (int t = 0; t < 4; ++t)
                    pre[t] = MFMA16(xxA[ks], *(const bf16x8*)&s_w[buf][(ks * 4 + t) * 512 + lane * 8], pre[t]);

            // h = tanh(pre); div += (1-h^2)*q; h -> transpose buffer
            #pragma unroll
            for (int t = 0; t < 4; ++t)
                #pragma unroll
                for (int r = 0; r < 4; ++r){
                    const float h = fast_tanh(pre[t][r]);
                    divst[r] += (1.f - h * h) * upk(q_pk[nc][t][r >> 1], r & 1);
                    tw[(l4 * 4 + r) * 72 + t * 16 + l15] = f2bf(h);
                }

            // GEMM2: dx += h@W2  (K-slice 64)
            #pragma unroll
            for (int ksl = 0; ksl < 2; ++ksl){
                const bf16x8 hA = *(const bf16x8*)&tw[l15 * 72 + ksl * 32 + l4 * 8];
                #pragma unroll
                for (int nt = 0; nt < 8; ++nt)
                    acc[nt] = MFMA16(hA, *(const bf16x8*)&s_w[buf][8192 + (ksl * 8 + nt) * 512 + lane * 8], acc[nt]);
            }
        }

        // ---- stage epilogue fused with xx transpose ----
        const float adt = (stg == 2) ? 0.25f : 0.125f;
        #pragma unroll
        for (int p = 0; p < 2; ++p){
            #pragma unroll
            for (int t = 0; t < 4; ++t){
                const int nt = p * 4 + t;
                const float b2v = s_b2[nt * 16 + l15];
                #pragma unroll
                for (int rr = 0; rr < 2; ++rr){
                    const float d0 = acc[nt][2 * rr]     + b2v;
                    const float d1 = acc[nt][2 * rr + 1] + b2v;
                    const float c0 = upk(dxc_pk[nt][rr], 0) + wcur * d0;
                    const float c1 = upk(dxc_pk[nt][rr], 1) + wcur * d1;
                    float xn0, xn1;
                    if (stg < 3){
                        dxc_pk[nt][rr] = pk2(c0, c1);
                        xn0 = xs[nt][2 * rr]     + adt * d0;
                        xn1 = xs[nt][2 * rr + 1] + adt * d1;
                    } else {
                        dxc_pk[nt][rr] = 0u;
                        xs[nt][2 * rr]     += (0.25f / 6.f) * c0;
                        xs[nt][2 * rr + 1] += (0.25f / 6.f) * c1;
                        xn0 = xs[nt][2 * rr]; xn1 = xs[nt][2 * rr + 1];
                    }
                    if (st < 15){
                        tw[(l4 * 4 + 2 * rr    ) * 72 + t * 16 + l15] = f2bf(xn0);
                        tw[(l4 * 4 + 2 * rr + 1) * 72 + t * 16 + l15] = f2bf(xn1);
                    }
                    acc[nt][2 * rr] = 0.f; acc[nt][2 * rr + 1] = 0.f;
                }
            }
            if (st < 15){
                #pragma unroll
                for (int ksl = 0; ksl < 2; ++ksl)
                    xxA[p * 2 + ksl] = *(const bf16x8*)&tw[l15 * 72 + ksl * 32 + l4 * 8];
            }
        }
        #pragma unroll
        for (int r = 0; r < 4; ++r) divacc[r] += wcur * divst[r];
    }

    // ---- outputs ----
    #pragma unroll
    for (int nt = 0; nt < 8; ++nt)
        #pragma unroll
        for (int r = 0; r < 4; ++r)
            y_out[(size_t)(rbase + l4 * 4 + r) * 128 + nt * 16 + l15] = xs[nt][r];

    #pragma unroll
    for (int r = 0; r < 4; ++r){
        float d = divacc[r];
        d += __shfl_xor(d, 1);
        d += __shfl_xor(d, 2);
        d += __shfl_xor(d, 4);
        d += __shfl_xor(d, 8);
        if (l15 == 0){
            const int row = rbase + l4 * 4 + r;
            lp_out[row] = logpx[row] - (0.25f / 6.f) * d;
        }
    }
}

extern "C" void kernel_launch(void* const* d_in, const int* in_sizes, int n_in,
                              void* d_out, int out_size, void* d_ws, size_t ws_size,
                              hipStream_t stream) {
    const float* x     = (const float*)d_in[0];
    const float* logpx = (const float*)d_in[1];
    const float* cond  = (const float*)d_in[2];
    const float* e     = (const float*)d_in[3];
    const float* W1    = (const float*)d_in[4];
    const float* Wc    = (const float*)d_in[5];
    const float* bt    = (const float*)d_in[6];
    const float* b1    = (const float*)d_in[7];
    const float* W2    = (const float*)d_in[8];
    const float* b2    = (const float*)d_in[9];

    u16* wp = (u16*)d_ws;                       // 5*65536 u16 = 640 KB
    float* y_out  = (float*)d_out;
    float* lp_out = y_out + (size_t)32768 * 128;

    hipLaunchKernelGGL(pack_weights_kernel, dim3(1280), dim3(256), 0, stream, W1, W2, Wc, wp);
    hipLaunchKernelGGL(cnf_mfma2_kernel, dim3(512), dim3(256), 0, stream,
                       x, logpx, cond, e, b1, wp, bt, b2, y_out, lp_out);
}